// Round 1
// baseline (583.494 us; speedup 1.0000x reference)
//
#include <hip/hip_runtime.h>
#include <cstdint>

// out[b,s,o] = sum_k in[b,s,k] * lut[w[o,k]] + bias[o]
// GEMM: M=8192, N=4096, K=4096, fp32 out, f16 MFMA path.
//
// R4: 256x256 tile, BK=64, 8 waves (2Mx4N), 8-phase-style schedule.
//  - boundary prefetch of next K-tile (8 x global_load_lds w=16) + COUNTED
//    s_waitcnt vmcnt(8): the 8 just-issued loads stay in flight across the
//    barrier (T3+T4); never drain to 0 in the main loop.
//  - 4 compute phases/tile, 16 MFMA each, raw s_barrier (no __syncthreads ->
//    no compiler vmcnt(0) drain), lgkmcnt(0)+sched_barrier(0) (rule 18),
//    s_setprio(1) around MFMA clusters (T5).
//  - XOR chunk swizzle kept from R3: LDS slot (row,c) holds global chunk
//    c^(row&7); linear LDS dest + pre-swizzled global src. 0 bank conflicts.
//  - XCD-aware block swizzle (512 blocks, 512%8==0 -> bijective).
// R3 (prev): 128x128 m97-structure, gemm 318us = 864 TF (structure ceiling,
// MfmaUtil 39%). Target here: ~1500 TF, MfmaUtil ~60%.

static constexpr int Md = 8192;
static constexpr int Nd = 4096;
static constexpr int Kd = 4096;
static constexpr int NKT = Kd / 64;

typedef _Float16 half8 __attribute__((ext_vector_type(8)));
typedef float f32x4 __attribute__((ext_vector_type(4)));

__device__ __forceinline__ void async_copy16(const _Float16* g, _Float16* l) {
  __builtin_amdgcn_global_load_lds((const __attribute__((address_space(1))) void*)g,
                                   (__attribute__((address_space(3))) void*)l, 16, 0, 0);
}

// ---- convert input fp32 -> fp16, 8 elems/thread ----
__global__ __launch_bounds__(256) void cvt_a(const float* __restrict__ in,
                                             _Float16* __restrict__ out) {
  const size_t i = (size_t)blockIdx.x * 256 + threadIdx.x;
  const float4 x = ((const float4*)in)[2 * i];
  const float4 y = ((const float4*)in)[2 * i + 1];
  half8 h;
  h[0] = (_Float16)x.x; h[1] = (_Float16)x.y; h[2] = (_Float16)x.z; h[3] = (_Float16)x.w;
  h[4] = (_Float16)y.x; h[5] = (_Float16)y.y; h[6] = (_Float16)y.z; h[7] = (_Float16)y.w;
  *(half8*)(out + 8 * i) = h;
}

// ---- dequant weight idx -> fp16 via LDS-cached 256-entry LUT ----
__global__ __launch_bounds__(256) void dequant_b(const int* __restrict__ w,
                                                 const float* __restrict__ lut,
                                                 _Float16* __restrict__ out) {
  __shared__ float slut[256];
  slut[threadIdx.x] = lut[threadIdx.x];
  __syncthreads();
  const size_t i = (size_t)blockIdx.x * 256 + threadIdx.x;
  const int4 a = ((const int4*)w)[2 * i];
  const int4 b = ((const int4*)w)[2 * i + 1];
  half8 h;
  h[0] = (_Float16)slut[a.x]; h[1] = (_Float16)slut[a.y];
  h[2] = (_Float16)slut[a.z]; h[3] = (_Float16)slut[a.w];
  h[4] = (_Float16)slut[b.x]; h[5] = (_Float16)slut[b.y];
  h[6] = (_Float16)slut[b.z]; h[7] = (_Float16)slut[b.w];
  *(half8*)(out + 8 * i) = h;
}

// ---- C[M][N] = A[M][K] * Bt[N][K]^T + bias ----
// 256x256 tile, BK=64, 8 waves (wm 0..1, wn 0..3), per-wave 128x64 output:
// acc[8][4] of 16x16x32 f16 MFMA.
__global__ __launch_bounds__(512, 2) void gemm_f16(const _Float16* __restrict__ A,
                                                   const _Float16* __restrict__ Bt,
                                                   const float* __restrict__ bias,
                                                   float* __restrict__ C) {
  // 2 K-tile double buffer: 2 * (256x64 A + 256x64 B) fp16 = 128 KiB
  __shared__ __align__(16) _Float16 As[2][256 * 64];
  __shared__ __align__(16) _Float16 Bs[2][256 * 64];

  const int tid = threadIdx.x;
  const int lane = tid & 63;
  const int wave = tid >> 6;
  const int wm = wave >> 2;  // 0..1
  const int wn = wave & 3;   // 0..3

  // XCD swizzle: 512 blocks -> 8 chunks of 64 consecutive on one XCD.
  // bm fastest inside chunk: the chunk's 2 B-panels (2x2MB) stay L2-resident.
  const int bid0 = blockIdx.x + blockIdx.y * gridDim.x;  // grid (32,16)
  const int bid = (bid0 & 7) * 64 + (bid0 >> 3);
  const int bm = bid & 31;
  const int bn = bid >> 5;

  // ---- staging addresses: 512 thr x 16B = 64 rows/issuance, 4 per half op.
  // LDS dest is linear (wave-uniform + lane*16); swizzle applied on the
  // GLOBAL source chunk: LDS slot (tid&7) receives global chunk (tid&7)^(row&7).
  const int trow = tid >> 3;                 // 0..63 (row within 64-row group)
  const int tcol = tid & 7;                  // LDS 16B-chunk slot
  const int gch = tcol ^ (trow & 7);         // swizzled global chunk
  const _Float16* ag = A + (size_t)(bm * 256 + trow) * Kd + gch * 8;
  const _Float16* bg = Bt + (size_t)(bn * 256 + trow) * Kd + gch * 8;
  const int lds_off = trow * 64 + tcol * 8;  // elements

  auto stage = [&](int buf, int kt) {
#pragma unroll
    for (int ht = 0; ht < 4; ++ht) {
      async_copy16(ag + (size_t)kt * 64 + (size_t)ht * (64 * Kd),
                   &As[buf][lds_off + ht * 4096]);
      async_copy16(bg + (size_t)kt * 64 + (size_t)ht * (64 * Kd),
                   &Bs[buf][lds_off + ht * 4096]);
    }
  };

  // ---- fragment addressing: global chunk kc of row r sits at slot kc^(r&7)
  const int fr = lane & 15;
  const int fq = lane >> 4;
  const int e = fr & 7;
  const int s0 = (fq ^ e) * 8;        // ks=0 chunk fq
  const int s1 = ((4 | fq) ^ e) * 8;  // ks=1 chunk 4+fq

  f32x4 acc[8][4] = {};

  stage(0, 0);  // prologue: tile 0 -> buf 0

  for (int kt = 0; kt < NKT; ++kt) {
    const int cur = kt & 1;
    if (kt + 1 < NKT) {
      stage(cur ^ 1, kt + 1);  // 8 loads for tile kt+1 into other buffer
      // wait for tile kt's 8 (oldest); keep tile kt+1's 8 in flight
      asm volatile("s_waitcnt vmcnt(8)" ::: "memory");
    } else {
      asm volatile("s_waitcnt vmcnt(0)" ::: "memory");
    }
    __builtin_amdgcn_s_barrier();  // all waves' tile-kt loads landed

    const _Float16* as = &As[cur][(wm * 128 + fr) * 64];
    const _Float16* bs = &Bs[cur][(wn * 64 + fr) * 64];

    half8 a[4][2], b0[2][2], b1[2][2];

    // ---- phase 0: read a(m-half 0) + b0(n-half 0); MFMA quadrant (0,0)
#pragma unroll
    for (int i = 0; i < 4; ++i) {
      a[i][0] = *(const half8*)(as + i * 16 * 64 + s0);
      a[i][1] = *(const half8*)(as + i * 16 * 64 + s1);
    }
#pragma unroll
    for (int j = 0; j < 2; ++j) {
      b0[j][0] = *(const half8*)(bs + j * 16 * 64 + s0);
      b0[j][1] = *(const half8*)(bs + j * 16 * 64 + s1);
    }
    __builtin_amdgcn_s_barrier();
    asm volatile("s_waitcnt lgkmcnt(0)" ::: "memory");
    __builtin_amdgcn_sched_barrier(0);
    __builtin_amdgcn_s_setprio(1);
#pragma unroll
    for (int i = 0; i < 4; ++i)
#pragma unroll
      for (int j = 0; j < 2; ++j) {
        acc[i][j] = __builtin_amdgcn_mfma_f32_16x16x32_f16(a[i][0], b0[j][0], acc[i][j], 0, 0, 0);
        acc[i][j] = __builtin_amdgcn_mfma_f32_16x16x32_f16(a[i][1], b0[j][1], acc[i][j], 0, 0, 0);
      }
    __builtin_amdgcn_s_setprio(0);
    __builtin_amdgcn_s_barrier();

    // ---- phase 1: read b1(n-half 1); MFMA quadrant (0,1)
#pragma unroll
    for (int j = 0; j < 2; ++j) {
      b1[j][0] = *(const half8*)(bs + (32 + j * 16) * 64 + s0);
      b1[j][1] = *(const half8*)(bs + (32 + j * 16) * 64 + s1);
    }
    __builtin_amdgcn_s_barrier();
    asm volatile("s_waitcnt lgkmcnt(0)" ::: "memory");
    __builtin_amdgcn_sched_barrier(0);
    __builtin_amdgcn_s_setprio(1);
#pragma unroll
    for (int i = 0; i < 4; ++i)
#pragma unroll
      for (int j = 0; j < 2; ++j) {
        acc[i][2 + j] = __builtin_amdgcn_mfma_f32_16x16x32_f16(a[i][0], b1[j][0], acc[i][2 + j], 0, 0, 0);
        acc[i][2 + j] = __builtin_amdgcn_mfma_f32_16x16x32_f16(a[i][1], b1[j][1], acc[i][2 + j], 0, 0, 0);
      }
    __builtin_amdgcn_s_setprio(0);
    __builtin_amdgcn_s_barrier();

    // ---- phase 2: read a(m-half 1); MFMA quadrant (1,1)
#pragma unroll
    for (int i = 0; i < 4; ++i) {
      a[i][0] = *(const half8*)(as + (64 + i * 16) * 64 + s0);
      a[i][1] = *(const half8*)(as + (64 + i * 16) * 64 + s1);
    }
    __builtin_amdgcn_s_barrier();
    asm volatile("s_waitcnt lgkmcnt(0)" ::: "memory");
    __builtin_amdgcn_sched_barrier(0);
    __builtin_amdgcn_s_setprio(1);
#pragma unroll
    for (int i = 0; i < 4; ++i)
#pragma unroll
      for (int j = 0; j < 2; ++j) {
        acc[4 + i][2 + j] = __builtin_amdgcn_mfma_f32_16x16x32_f16(a[i][0], b1[j][0], acc[4 + i][2 + j], 0, 0, 0);
        acc[4 + i][2 + j] = __builtin_amdgcn_mfma_f32_16x16x32_f16(a[i][1], b1[j][1], acc[4 + i][2 + j], 0, 0, 0);
      }
    __builtin_amdgcn_s_setprio(0);
    __builtin_amdgcn_s_barrier();

    // ---- phase 3: no reads (a from phase 2, b0 from phase 0); quadrant (1,0)
    __builtin_amdgcn_s_setprio(1);
#pragma unroll
    for (int i = 0; i < 4; ++i)
#pragma unroll
      for (int j = 0; j < 2; ++j) {
        acc[4 + i][j] = __builtin_amdgcn_mfma_f32_16x16x32_f16(a[i][0], b0[j][0], acc[4 + i][j], 0, 0, 0);
        acc[4 + i][j] = __builtin_amdgcn_mfma_f32_16x16x32_f16(a[i][1], b0[j][1], acc[4 + i][j], 0, 0, 0);
      }
    __builtin_amdgcn_s_setprio(0);
    __builtin_amdgcn_s_barrier();
  }

  // ---- epilogue: C/D layout col = lane&15, row = (lane>>4)*4 + reg
  const int ccol0 = bn * 256 + wn * 64 + fr;
  const int crow0 = bm * 256 + wm * 128 + fq * 4;
  float bv[4];
#pragma unroll
  for (int j = 0; j < 4; ++j) bv[j] = bias[ccol0 + j * 16];
#pragma unroll
  for (int i = 0; i < 8; ++i) {
#pragma unroll
    for (int r = 0; r < 4; ++r) {
      float* cp = C + (size_t)(crow0 + i * 16 + r) * Nd + ccol0;
#pragma unroll
      for (int j = 0; j < 4; ++j) cp[j * 16] = acc[i][j][r] + bv[j];
    }
  }
}

extern "C" void kernel_launch(void* const* d_in, const int* in_sizes, int n_in,
                              void* d_out, int out_size, void* d_ws, size_t ws_size,
                              hipStream_t stream) {
  const float* inp = (const float*)d_in[0];
  const float* lut = (const float*)d_in[1];
  const int* wgt = (const int*)d_in[2];
  const float* bias = (const float*)d_in[3];
  float* out = (float*)d_out;

  _Float16* Ah = (_Float16*)d_ws;
  _Float16* Bh = (_Float16*)d_ws + (size_t)Md * Kd;

  cvt_a<<<(Md * (size_t)Kd) / (8 * 256), 256, 0, stream>>>(inp, Ah);
  dequant_b<<<((size_t)Nd * Kd) / (8 * 256), 256, 0, stream>>>(wgt, lut, Bh);

  dim3 grid(Md / 256, Nd / 256);  // (32, 16) = 512 blocks
  gemm_f16<<<grid, 512, 0, stream>>>(Ah, Bh, bias, out);
}

// Round 2
// 530.589 us; speedup vs baseline: 1.0997x; 1.0997x over previous
//
#include <hip/hip_runtime.h>
#include <cstdint>

// out[b,s,o] = sum_k in[b,s,k] * lut[w[o,k]] + bias[o]
// GEMM: M=8192, N=4096, K=4096, fp32 out, f16 MFMA path.
//
// R5: R4 (256x256 tile, BK=64, 8 waves, 4-phase quadrant schedule, counted
// vmcnt(8), raw s_barrier, setprio) + INLINE-ASM ds_read_b128 fragment loads.
// Theory: hipcc's alias model sees global_load_lds (VMEM->LDS write) vs deref
// LDS reads and inserts its own s_waitcnt vmcnt(0) before phase-0 reads,
// draining the tile-kt+1 prefetch each iteration (R4: MfmaUtil 33.6%, 350us,
// WORSE than the 2-barrier 128^2 R3 at 318us). asm ds_reads remove the RAW
// edge; only our counted waits remain. rule-18 fence (lgkmcnt(0) +
// sched_barrier(0)) already in place before each MFMA cluster.
// Predicted: gemm ~220us, MfmaUtil ~55%.

static constexpr int Md = 8192;
static constexpr int Nd = 4096;
static constexpr int Kd = 4096;
static constexpr int NKT = Kd / 64;

typedef _Float16 half8 __attribute__((ext_vector_type(8)));
typedef float f32x4 __attribute__((ext_vector_type(4)));

__device__ __forceinline__ void async_copy16(const _Float16* g, _Float16* l) {
  __builtin_amdgcn_global_load_lds((const __attribute__((address_space(1))) void*)g,
                                   (__attribute__((address_space(3))) void*)l, 16, 0, 0);
}

// LDS read via raw asm: compiler cannot see an LDS read -> no conservative
// vmcnt drains against global_load_lds. addr = 32-bit LDS byte offset
// (low 32 bits of the generic pointer on AMDGPU).
__device__ __forceinline__ half8 lds_read_b128(uint32_t addr) {
  half8 r;
  asm volatile("ds_read_b128 %0, %1" : "=v"(r) : "v"(addr));
  return r;
}

// ---- convert input fp32 -> fp16, 8 elems/thread ----
__global__ __launch_bounds__(256) void cvt_a(const float* __restrict__ in,
                                             _Float16* __restrict__ out) {
  const size_t i = (size_t)blockIdx.x * 256 + threadIdx.x;
  const float4 x = ((const float4*)in)[2 * i];
  const float4 y = ((const float4*)in)[2 * i + 1];
  half8 h;
  h[0] = (_Float16)x.x; h[1] = (_Float16)x.y; h[2] = (_Float16)x.z; h[3] = (_Float16)x.w;
  h[4] = (_Float16)y.x; h[5] = (_Float16)y.y; h[6] = (_Float16)y.z; h[7] = (_Float16)y.w;
  *(half8*)(out + 8 * i) = h;
}

// ---- dequant weight idx -> fp16 via LDS-cached 256-entry LUT ----
__global__ __launch_bounds__(256) void dequant_b(const int* __restrict__ w,
                                                 const float* __restrict__ lut,
                                                 _Float16* __restrict__ out) {
  __shared__ float slut[256];
  slut[threadIdx.x] = lut[threadIdx.x];
  __syncthreads();
  const size_t i = (size_t)blockIdx.x * 256 + threadIdx.x;
  const int4 a = ((const int4*)w)[2 * i];
  const int4 b = ((const int4*)w)[2 * i + 1];
  half8 h;
  h[0] = (_Float16)slut[a.x]; h[1] = (_Float16)slut[a.y];
  h[2] = (_Float16)slut[a.z]; h[3] = (_Float16)slut[a.w];
  h[4] = (_Float16)slut[b.x]; h[5] = (_Float16)slut[b.y];
  h[6] = (_Float16)slut[b.z]; h[7] = (_Float16)slut[b.w];
  *(half8*)(out + 8 * i) = h;
}

// ---- C[M][N] = A[M][K] * Bt[N][K]^T + bias ----
// 256x256 tile, BK=64, 8 waves (wm 0..1, wn 0..3), per-wave 128x64 output:
// acc[8][4] of 16x16x32 f16 MFMA.
__global__ __launch_bounds__(512, 2) void gemm_f16(const _Float16* __restrict__ A,
                                                   const _Float16* __restrict__ Bt,
                                                   const float* __restrict__ bias,
                                                   float* __restrict__ C) {
  // 2 K-tile double buffer: 2 * (256x64 A + 256x64 B) fp16 = 128 KiB
  __shared__ __align__(16) _Float16 As[2][256 * 64];
  __shared__ __align__(16) _Float16 Bs[2][256 * 64];

  const int tid = threadIdx.x;
  const int lane = tid & 63;
  const int wave = tid >> 6;
  const int wm = wave >> 2;  // 0..1
  const int wn = wave & 3;   // 0..3

  // XCD swizzle: 512 blocks -> 8 chunks of 64 consecutive on one XCD.
  const int bid0 = blockIdx.x + blockIdx.y * gridDim.x;  // grid (32,16)
  const int bid = (bid0 & 7) * 64 + (bid0 >> 3);
  const int bm = bid & 31;
  const int bn = bid >> 5;

  // ---- staging: 512 thr x 16B = 64 rows/issuance, 4 per half op.
  // LDS dest linear; swizzle on the GLOBAL source chunk:
  // LDS slot (tid&7) receives global chunk (tid&7)^(row&7).
  const int trow = tid >> 3;                 // 0..63
  const int tcol = tid & 7;                  // LDS 16B-chunk slot
  const int gch = tcol ^ (trow & 7);         // swizzled global chunk
  const _Float16* ag = A + (size_t)(bm * 256 + trow) * Kd + gch * 8;
  const _Float16* bg = Bt + (size_t)(bn * 256 + trow) * Kd + gch * 8;
  const int lds_off = trow * 64 + tcol * 8;  // elements

  auto stage = [&](int buf, int kt) {
#pragma unroll
    for (int ht = 0; ht < 4; ++ht) {
      async_copy16(ag + (size_t)kt * 64 + (size_t)ht * (64 * Kd),
                   &As[buf][lds_off + ht * 4096]);
      async_copy16(bg + (size_t)kt * 64 + (size_t)ht * (64 * Kd),
                   &Bs[buf][lds_off + ht * 4096]);
    }
  };

  // ---- fragment addressing (asm ds_read): 32-bit LDS byte offsets.
  // Global chunk kc of row r sits at slot kc^(r&7); row stride 128 B.
  const int fr = lane & 15;
  const int fq = lane >> 4;
  const int e = fr & 7;
  const uint32_t as0 = (uint32_t)(uintptr_t)&As[0][0];
  const uint32_t bs0 = (uint32_t)(uintptr_t)&Bs[0][0];
  const uint32_t s0b = (uint32_t)((fq ^ e) * 16);        // ks=0 chunk fq
  const uint32_t s1b = (uint32_t)(((4 | fq) ^ e) * 16);  // ks=1 chunk 4+fq
  const uint32_t arow = as0 + (uint32_t)((wm * 128 + fr) * 128);
  const uint32_t brow = bs0 + (uint32_t)((wn * 64 + fr) * 128);

  f32x4 acc[8][4] = {};

  stage(0, 0);  // prologue: tile 0 -> buf 0

  for (int kt = 0; kt < NKT; ++kt) {
    const uint32_t cb = (uint32_t)(kt & 1) * 32768u;  // buffer byte offset
    if (kt + 1 < NKT) {
      stage((kt & 1) ^ 1, kt + 1);  // 8 loads for tile kt+1 into other buffer
      // wait for tile kt's 8 (oldest); keep tile kt+1's 8 in flight
      asm volatile("s_waitcnt vmcnt(8)" ::: "memory");
    } else {
      asm volatile("s_waitcnt vmcnt(0)" ::: "memory");
    }
    __builtin_amdgcn_s_barrier();  // all waves' tile-kt loads landed

    const uint32_t a0 = arow + cb + s0b;  // ks=0 a-frag base
    const uint32_t a1 = arow + cb + s1b;  // ks=1
    const uint32_t b0a = brow + cb + s0b;
    const uint32_t b1a = brow + cb + s1b;

    half8 a[4][2], b0[2][2], b1[2][2];

    // ---- phase 0: read a(m-half 0) + b0(n-half 0); MFMA quadrant (0,0)
#pragma unroll
    for (int i = 0; i < 4; ++i) {
      a[i][0] = lds_read_b128(a0 + i * 2048);
      a[i][1] = lds_read_b128(a1 + i * 2048);
    }
#pragma unroll
    for (int j = 0; j < 2; ++j) {
      b0[j][0] = lds_read_b128(b0a + j * 2048);
      b0[j][1] = lds_read_b128(b1a + j * 2048);
    }
    __builtin_amdgcn_s_barrier();
    asm volatile("s_waitcnt lgkmcnt(0)" ::: "memory");
    __builtin_amdgcn_sched_barrier(0);
    __builtin_amdgcn_s_setprio(1);
#pragma unroll
    for (int i = 0; i < 4; ++i)
#pragma unroll
      for (int j = 0; j < 2; ++j) {
        acc[i][j] = __builtin_amdgcn_mfma_f32_16x16x32_f16(a[i][0], b0[j][0], acc[i][j], 0, 0, 0);
        acc[i][j] = __builtin_amdgcn_mfma_f32_16x16x32_f16(a[i][1], b0[j][1], acc[i][j], 0, 0, 0);
      }
    __builtin_amdgcn_s_setprio(0);
    __builtin_amdgcn_s_barrier();

    // ---- phase 1: read b1(n-half 1); MFMA quadrant (0,1)
#pragma unroll
    for (int j = 0; j < 2; ++j) {
      b1[j][0] = lds_read_b128(b0a + 4096 + j * 2048);
      b1[j][1] = lds_read_b128(b1a + 4096 + j * 2048);
    }
    __builtin_amdgcn_s_barrier();
    asm volatile("s_waitcnt lgkmcnt(0)" ::: "memory");
    __builtin_amdgcn_sched_barrier(0);
    __builtin_amdgcn_s_setprio(1);
#pragma unroll
    for (int i = 0; i < 4; ++i)
#pragma unroll
      for (int j = 0; j < 2; ++j) {
        acc[i][2 + j] = __builtin_amdgcn_mfma_f32_16x16x32_f16(a[i][0], b1[j][0], acc[i][2 + j], 0, 0, 0);
        acc[i][2 + j] = __builtin_amdgcn_mfma_f32_16x16x32_f16(a[i][1], b1[j][1], acc[i][2 + j], 0, 0, 0);
      }
    __builtin_amdgcn_s_setprio(0);
    __builtin_amdgcn_s_barrier();

    // ---- phase 2: read a(m-half 1); MFMA quadrant (1,1)
#pragma unroll
    for (int i = 0; i < 4; ++i) {
      a[i][0] = lds_read_b128(a0 + 8192 + i * 2048);
      a[i][1] = lds_read_b128(a1 + 8192 + i * 2048);
    }
    __builtin_amdgcn_s_barrier();
    asm volatile("s_waitcnt lgkmcnt(0)" ::: "memory");
    __builtin_amdgcn_sched_barrier(0);
    __builtin_amdgcn_s_setprio(1);
#pragma unroll
    for (int i = 0; i < 4; ++i)
#pragma unroll
      for (int j = 0; j < 2; ++j) {
        acc[4 + i][2 + j] = __builtin_amdgcn_mfma_f32_16x16x32_f16(a[i][0], b1[j][0], acc[4 + i][2 + j], 0, 0, 0);
        acc[4 + i][2 + j] = __builtin_amdgcn_mfma_f32_16x16x32_f16(a[i][1], b1[j][1], acc[4 + i][2 + j], 0, 0, 0);
      }
    __builtin_amdgcn_s_setprio(0);
    __builtin_amdgcn_s_barrier();

    // ---- phase 3: no reads (a from phase 2, b0 from phase 0); quadrant (1,0)
    __builtin_amdgcn_s_setprio(1);
#pragma unroll
    for (int i = 0; i < 4; ++i)
#pragma unroll
      for (int j = 0; j < 2; ++j) {
        acc[4 + i][j] = __builtin_amdgcn_mfma_f32_16x16x32_f16(a[i][0], b0[j][0], acc[4 + i][j], 0, 0, 0);
        acc[4 + i][j] = __builtin_amdgcn_mfma_f32_16x16x32_f16(a[i][1], b0[j][1], acc[4 + i][j], 0, 0, 0);
      }
    __builtin_amdgcn_s_setprio(0);
    __builtin_amdgcn_s_barrier();
  }

  // ---- epilogue: C/D layout col = lane&15, row = (lane>>4)*4 + reg
  const int ccol0 = bn * 256 + wn * 64 + fr;
  const int crow0 = bm * 256 + wm * 128 + fq * 4;
  float bv[4];
#pragma unroll
  for (int j = 0; j < 4; ++j) bv[j] = bias[ccol0 + j * 16];
#pragma unroll
  for (int i = 0; i < 8; ++i) {
#pragma unroll
    for (int r = 0; r < 4; ++r) {
      float* cp = C + (size_t)(crow0 + i * 16 + r) * Nd + ccol0;
#pragma unroll
      for (int j = 0; j < 4; ++j) cp[j * 16] = acc[i][j][r] + bv[j];
    }
  }
}

extern "C" void kernel_launch(void* const* d_in, const int* in_sizes, int n_in,
                              void* d_out, int out_size, void* d_ws, size_t ws_size,
                              hipStream_t stream) {
  const float* inp = (const float*)d_in[0];
  const float* lut = (const float*)d_in[1];
  const int* wgt = (const int*)d_in[2];
  const float* bias = (const float*)d_in[3];
  float* out = (float*)d_out;

  _Float16* Ah = (_Float16*)d_ws;
  _Float16* Bh = (_Float16*)d_ws + (size_t)Md * Kd;

  cvt_a<<<(Md * (size_t)Kd) / (8 * 256), 256, 0, stream>>>(inp, Ah);
  dequant_b<<<((size_t)Nd * Kd) / (8 * 256), 256, 0, stream>>>(wgt, lut, Bh);

  dim3 grid(Md / 256, Nd / 256);  // (32, 16) = 512 blocks
  gemm_f16<<<grid, 512, 0, stream>>>(Ah, Bh, bias, out);
}